// Round 2
// baseline (147.865 us; speedup 1.0000x reference)
//
#include <hip/hip_runtime.h>
#include <hip/hip_bf16.h>
#include <math.h>

// Problem constants (from reference): NUM_MAPS=512, ZG=512, HID=96, SEQ=8,
// H1=3, H2=16, NPROC=8, NUM_BLOCKS=2. All inputs float32, output float32
// (2,4,512). (R1 NaN post-mortem: inputs are fp32, NOT bf16 — reading fp32
// buffers as u16 produced NaN bit patterns.)

// Workspace layout (fp32): [0,512) alpha, [512,608) q, [608, 608+18432) QKV1
// QKV1 index: proc*2304 + mat*768 + s*96 + h   (mat: 0=Qk,1=Kk,2=Vv)
#define WS_ALPHA 0
#define WS_Q     512
#define WS_QKV   608

// ---------------------------------------------------------------------------
// K1: alpha = sigmoid(x@Wa+ba); q = relu(x@Wqr+bqr); QKV1 = K @ W{q,k,v}1
// blocks 0..71: QKV (9 blocks/proc, 1 dot of length 512 per thread)
// blocks 72,73: alpha (256 outputs each); block 74: q (96 outputs)
// ---------------------------------------------------------------------------
__global__ __launch_bounds__(256) void k1_qkv_alpha_q(
    const float* __restrict__ x, const float* __restrict__ Wa,
    const float* __restrict__ ba, const float* __restrict__ Wqr,
    const float* __restrict__ bqr, const float* __restrict__ P,
    const float* __restrict__ Wq1, const float* __restrict__ Wk1,
    const float* __restrict__ Wv1, float* __restrict__ ws)
{
    __shared__ float sm[8 * 512];   // K tile (s-major) or x vector
    const int blk = blockIdx.x, tid = threadIdx.x;

    if (blk < 72) {
        const int proc = blk / 9, c = blk % 9;
        // K[s][m] = P[proc, m, s];  P row m is 8 contiguous floats
        for (int m = tid; m < 512; m += 256) {
            const float* pr = P + proc * 4096 + m * 8;
            #pragma unroll
            for (int s = 0; s < 8; ++s) sm[s * 512 + m] = pr[s];
        }
        __syncthreads();
        const int r = c * 256 + tid;          // 0..2303 within proc
        const int mat = r / 768, r2 = r % 768;
        const int s = r2 / 96, h = r2 % 96;
        const float* W = (mat == 0 ? Wq1 : (mat == 1 ? Wk1 : Wv1))
                         + proc * 49152 + h;
        const float* Ks = sm + s * 512;
        float acc = 0.f;
        #pragma unroll 8
        for (int m = 0; m < 512; ++m) acc += Ks[m] * W[m * 96];
        ws[WS_QKV + proc * 2304 + r] = acc;
    } else if (blk < 74) {
        for (int k = tid; k < 512; k += 256) sm[k] = x[k];
        __syncthreads();
        const int m = (blk - 72) * 256 + tid;
        float acc = ba[m];
        #pragma unroll 8
        for (int k = 0; k < 512; ++k) acc += sm[k] * Wa[k * 512 + m];
        ws[WS_ALPHA + m] = 1.f / (1.f + __expf(-acc));
    } else {
        for (int k = tid; k < 512; k += 256) sm[k] = x[k];
        __syncthreads();
        if (tid < 96) {
            float acc = bqr[tid];
            #pragma unroll 8
            for (int k = 0; k < 512; ++k) acc += sm[k] * Wqr[k * 96 + tid];
            ws[WS_Q + tid] = fmaxf(acc, 0.f);
        }
    }
}

// ---------------------------------------------------------------------------
// K2: one block per processor. attn1(H1=3,d=32) -> fc1 -> stage2 attn(H2=16,
// d=6) -> fc2 -> O@Wo fused with De*gate, alpha-mix, regs, offs. fp32 out.
// ---------------------------------------------------------------------------
__global__ __launch_bounds__(512) void k2_attn_out(
    const float* __restrict__ gate, const float* __restrict__ De,
    const float* __restrict__ regs, const float* __restrict__ fc1,
    const float* __restrict__ Wq2, const float* __restrict__ Wk2,
    const float* __restrict__ Wv2, const float* __restrict__ fc2,
    const float* __restrict__ Wo, const float* __restrict__ ws,
    float* __restrict__ out)
{
    const int proc = blockIdx.x, tid = threadIdx.x;
    __shared__ float sQk[768], sKk[768], sVv[768], sH[768], sH2[768];
    __shared__ float sK2[768], sV2[768];
    __shared__ float sq[96], sQq[96], sO[96], sOf[96], sS[192], sg[8];
    const float rs = 0.10206207261596577f;  // 1/sqrt(96) — scale uses full D

    const float* qkv = ws + WS_QKV + proc * 2304;
    for (int i = tid; i < 768; i += 512) {
        sQk[i] = qkv[i]; sKk[i] = qkv[768 + i]; sVv[i] = qkv[1536 + i];
    }
    if (tid < 96) sq[tid] = ws[WS_Q + tid];
    if (tid < 8)  sg[tid] = gate[tid];
    __syncthreads();

    // attn1 logits: 3 heads x 8 q x 8 k
    if (tid < 192) {
        const int h0 = tid / 64, rem = tid % 64, si = rem / 8, sk = rem % 8;
        float acc = 0.f;
        #pragma unroll
        for (int d = 0; d < 32; ++d)
            acc += sQk[si * 96 + h0 * 32 + d] * sKk[sk * 96 + h0 * 32 + d];
        sS[tid] = acc * rs;
    }
    __syncthreads();

    // softmax rows + O + residual: 24 (head, si) rows
    if (tid < 24) {
        const int h0 = tid / 8, si = tid % 8;
        const float* row = sS + h0 * 64 + si * 8;
        float mx = row[0];
        #pragma unroll
        for (int k = 1; k < 8; ++k) mx = fmaxf(mx, row[k]);
        float e[8], sum = 0.f;
        #pragma unroll
        for (int k = 0; k < 8; ++k) { e[k] = __expf(row[k] - mx); sum += e[k]; }
        const float inv = 1.f / sum;
        #pragma unroll
        for (int d = 0; d < 32; ++d) {
            float o = 0.f;
            #pragma unroll
            for (int k = 0; k < 8; ++k) o += e[k] * sVv[k * 96 + h0 * 32 + d];
            const int idx = si * 96 + h0 * 32 + d;
            sH[idx] = sQk[idx] + o * inv;
        }
    }
    __syncthreads();

    // fc1: H2 = H + relu(H @ fc1)
    for (int idx = tid; idx < 768; idx += 512) {
        const int s = idx / 96, j = idx % 96;
        const float* W = fc1 + proc * 9216 + j;
        const float* Hs = sH + s * 96;
        float acc = 0.f;
        #pragma unroll 8
        for (int i = 0; i < 96; ++i) acc += Hs[i] * W[i * 96];
        sH2[idx] = sH[idx] + fmaxf(acc, 0.f);
    }
    // Qq = q @ Wq2 (independent of fc1 output — same sync region)
    if (tid < 96) {
        const float* W = Wq2 + proc * 9216 + tid;
        float acc = 0.f;
        #pragma unroll 8
        for (int i = 0; i < 96; ++i) acc += sq[i] * W[i * 96];
        sQq[tid] = acc;
    }
    __syncthreads();

    // K2 = H2 @ Wk2, V2 = H2 @ Wv2
    for (int idx = tid; idx < 1536; idx += 512) {
        const int which = idx / 768, r = idx % 768;
        const int s = r / 96, j = r % 96;
        const float* W = (which ? Wv2 : Wk2) + proc * 9216 + j;
        const float* Hs = sH2 + s * 96;
        float acc = 0.f;
        #pragma unroll 8
        for (int i = 0; i < 96; ++i) acc += Hs[i] * W[i * 96];
        if (which) sV2[r] = acc; else sK2[r] = acc;
    }
    __syncthreads();

    // attn2: 16 heads, d=6, single query row; O = Qq + mha2
    if (tid < 16) {
        const int h0 = tid;
        float lg[8], mx = -1e30f;
        #pragma unroll
        for (int k = 0; k < 8; ++k) {
            float acc = 0.f;
            #pragma unroll
            for (int d = 0; d < 6; ++d)
                acc += sQq[h0 * 6 + d] * sK2[k * 96 + h0 * 6 + d];
            lg[k] = acc * rs; mx = fmaxf(mx, lg[k]);
        }
        float e[8], sum = 0.f;
        #pragma unroll
        for (int k = 0; k < 8; ++k) { e[k] = __expf(lg[k] - mx); sum += e[k]; }
        const float inv = 1.f / sum;
        #pragma unroll
        for (int d = 0; d < 6; ++d) {
            float o = 0.f;
            #pragma unroll
            for (int k = 0; k < 8; ++k) o += e[k] * sV2[k * 96 + h0 * 6 + d];
            sO[h0 * 6 + d] = sQq[h0 * 6 + d] + o * inv;
        }
    }
    __syncthreads();

    // fc2: Of = O + relu(O @ fc2)
    if (tid < 96) {
        const float* W = fc2 + proc * 9216 + tid;
        float acc = 0.f;
        #pragma unroll 8
        for (int i = 0; i < 96; ++i) acc += sO[i] * W[i * 96];
        sOf[tid] = sO[tid] + fmaxf(acc, 0.f);
    }
    __syncthreads();

    // Epilogue: trans[m] = Of @ Wo[:,m]; mix with de, alpha, regs, offs
    {
        const int m = tid;                       // 512 threads <-> 512 maps
        const float* W = Wo + proc * 49152 + m;
        float tr = 0.f;
        #pragma unroll 8
        for (int h = 0; h < 96; ++h) tr += sOf[h] * W[h * 512];
        const float* Dp = De + proc * 4096 + m * 8;
        float de = 0.f;
        #pragma unroll
        for (int s = 0; s < 8; ++s) de += Dp[s] * sg[s];
        const float a = ws[WS_ALPHA + m];
        const float mix = a * tr + (1.f - a) * de;
        const int pt = proc & 3;                 // {g1,b1,g2,b2}: gamma gets +1
        const float off = (pt == 0 || pt == 2) ? 1.f : 0.f;
        const float val = mix * regs[proc * 512 + m] + off;
        out[proc * 512 + m] = val;
    }
}

extern "C" void kernel_launch(void* const* d_in, const int* in_sizes, int n_in,
                              void* d_out, int out_size, void* d_ws, size_t ws_size,
                              hipStream_t stream)
{
    const float* gate = (const float*)d_in[0];
    const float* x    = (const float*)d_in[1];
    const float* Wa   = (const float*)d_in[2];
    const float* ba   = (const float*)d_in[3];
    const float* Wqr  = (const float*)d_in[4];
    const float* bqr  = (const float*)d_in[5];
    const float* P    = (const float*)d_in[6];
    const float* De   = (const float*)d_in[7];
    const float* regs = (const float*)d_in[8];
    const float* Wq1  = (const float*)d_in[9];
    const float* Wk1  = (const float*)d_in[10];
    const float* Wv1  = (const float*)d_in[11];
    const float* fc1  = (const float*)d_in[12];
    const float* Wq2  = (const float*)d_in[13];
    const float* Wk2  = (const float*)d_in[14];
    const float* Wv2  = (const float*)d_in[15];
    const float* fc2  = (const float*)d_in[16];
    const float* Wo   = (const float*)d_in[17];
    float* ws = (float*)d_ws;

    hipLaunchKernelGGL(k1_qkv_alpha_q, dim3(75), dim3(256), 0, stream,
                       x, Wa, ba, Wqr, bqr, P, Wq1, Wk1, Wv1, ws);
    hipLaunchKernelGGL(k2_attn_out, dim3(8), dim3(512), 0, stream,
                       gate, De, regs, fc1, Wq2, Wk2, Wv2, fc2, Wo, ws,
                       (float*)d_out);
}

// Round 3
// 116.649 us; speedup vs baseline: 1.2676x; 1.2676x over previous
//
#include <hip/hip_runtime.h>
#include <hip/hip_bf16.h>
#include <math.h>

// NUM_MAPS=512, ZG=512, HID=96, SEQ=8, H1=3, H2=16, NPROC=8. fp32 in/out.
// R2 post-mortem: latency-bound on HBM-cold weight loads (ws 0xAA poison of
// 268MB evicts L3 every iter). Fix: 4-way dot splits + unroll 32 => >=4x MLP,
// 4x shorter dependent chains; alpha 2->8 blocks.

#define WS_ALPHA 0
#define WS_Q     512
#define WS_QKV   608

// ---------------------------------------------------------------------------
// K1 grid (298 blocks x 256):
//  blk 0..287   : QKV1 = K @ W{q,k,v}1. 36 blk/proc, 64 outputs/blk,
//                 4 k-quarters (tid>>6), 128 loads/thread, unroll 32.
//  blk 288..295 : alpha. 64 outputs/blk, 4 k-quarters.
//  blk 296..297 : q. 64/32 outputs, 4 k-quarters.
// ---------------------------------------------------------------------------
__global__ __launch_bounds__(256) void k1_qkv_alpha_q(
    const float* __restrict__ x, const float* __restrict__ Wa,
    const float* __restrict__ ba, const float* __restrict__ Wqr,
    const float* __restrict__ bqr, const float* __restrict__ P,
    const float* __restrict__ Wq1, const float* __restrict__ Wk1,
    const float* __restrict__ Wv1, float* __restrict__ ws)
{
    __shared__ float sK[8 * 512];   // K tile (s-major) or x vector
    __shared__ float sp[256];       // partial sums
    const int blk = blockIdx.x, tid = threadIdx.x;

    if (blk < 288) {
        const int proc = blk / 36, c = blk % 36;
        // stage K[s][m] = P[proc,m,s] via float4 (1024 float4 = 4/thread)
        const float4* P4 = (const float4*)(P + proc * 4096);
        for (int i = tid; i < 1024; i += 256) {
            float4 v = P4[i];
            const int m = i >> 1, off = (i & 1) * 4;
            sK[(off + 0) * 512 + m] = v.x;
            sK[(off + 1) * 512 + m] = v.y;
            sK[(off + 2) * 512 + m] = v.z;
            sK[(off + 3) * 512 + m] = v.w;
        }
        __syncthreads();
        const int rl = tid & 63, qtr = tid >> 6;
        const int r = c * 64 + rl;                 // 0..2303 within proc
        const int mat = r / 768, r2 = r % 768;
        const int s = r2 / 96, h = r2 % 96;
        const float* W = (mat == 0 ? Wq1 : (mat == 1 ? Wk1 : Wv1))
                         + proc * 49152 + (qtr * 128) * 96 + h;
        const float* Ks = sK + s * 512 + qtr * 128;
        float acc = 0.f;
        #pragma unroll 32
        for (int m = 0; m < 128; ++m) acc += Ks[m] * W[m * 96];
        sp[tid] = acc;
        __syncthreads();
        if (qtr == 0) {
            acc = sp[tid] + sp[tid + 64] + sp[tid + 128] + sp[tid + 192];
            ws[WS_QKV + proc * 2304 + r] = acc;
        }
    } else if (blk < 296) {
        for (int k = tid; k < 512; k += 256) sK[k] = x[k];
        __syncthreads();
        const int ml = tid & 63, qtr = tid >> 6;
        const int m = (blk - 288) * 64 + ml;
        const float* W = Wa + (qtr * 128) * 512 + m;
        const float* xq = sK + qtr * 128;
        float acc = 0.f;
        #pragma unroll 32
        for (int k = 0; k < 128; ++k) acc += xq[k] * W[k * 512];
        sp[tid] = acc;
        __syncthreads();
        if (qtr == 0) {
            acc = sp[tid] + sp[tid + 64] + sp[tid + 128] + sp[tid + 192] + ba[m];
            ws[WS_ALPHA + m] = 1.f / (1.f + __expf(-acc));
        }
    } else {
        for (int k = tid; k < 512; k += 256) sK[k] = x[k];
        __syncthreads();
        const int hl = tid & 63, qtr = tid >> 6;
        const int h = (blk - 296) * 64 + hl;
        float acc = 0.f;
        if (h < 96) {
            const float* W = Wqr + (qtr * 128) * 96 + h;
            const float* xq = sK + qtr * 128;
            #pragma unroll 32
            for (int k = 0; k < 128; ++k) acc += xq[k] * W[k * 96];
        }
        sp[tid] = acc;
        __syncthreads();
        if (qtr == 0 && h < 96) {
            acc = sp[tid] + sp[tid + 64] + sp[tid + 128] + sp[tid + 192] + bqr[h];
            ws[WS_Q + h] = fmaxf(acc, 0.f);
        }
    }
}

// ---------------------------------------------------------------------------
// K2: one block per processor; unroll 32 on every 96-dot (3 vmcnt batches
// instead of 12 per phase).
// ---------------------------------------------------------------------------
__global__ __launch_bounds__(512) void k2_attn_out(
    const float* __restrict__ gate, const float* __restrict__ De,
    const float* __restrict__ regs, const float* __restrict__ fc1,
    const float* __restrict__ Wq2, const float* __restrict__ Wk2,
    const float* __restrict__ Wv2, const float* __restrict__ fc2,
    const float* __restrict__ Wo, const float* __restrict__ ws,
    float* __restrict__ out)
{
    const int proc = blockIdx.x, tid = threadIdx.x;
    __shared__ float sQk[768], sKk[768], sVv[768], sH[768], sH2[768];
    __shared__ float sK2[768], sV2[768];
    __shared__ float sq[96], sQq[96], sO[96], sOf[96], sS[192], sg[8];
    const float rs = 0.10206207261596577f;  // 1/sqrt(96)

    const float* qkv = ws + WS_QKV + proc * 2304;
    for (int i = tid; i < 768; i += 512) {
        sQk[i] = qkv[i]; sKk[i] = qkv[768 + i]; sVv[i] = qkv[1536 + i];
    }
    if (tid < 96) sq[tid] = ws[WS_Q + tid];
    if (tid < 8)  sg[tid] = gate[tid];
    __syncthreads();

    // attn1 logits: 3 heads x 8 q x 8 k
    if (tid < 192) {
        const int h0 = tid / 64, rem = tid % 64, si = rem / 8, sk = rem % 8;
        float acc = 0.f;
        #pragma unroll
        for (int d = 0; d < 32; ++d)
            acc += sQk[si * 96 + h0 * 32 + d] * sKk[sk * 96 + h0 * 32 + d];
        sS[tid] = acc * rs;
    }
    __syncthreads();

    // softmax + O + residual: 24 (head, si) rows
    if (tid < 24) {
        const int h0 = tid / 8, si = tid % 8;
        const float* row = sS + h0 * 64 + si * 8;
        float mx = row[0];
        #pragma unroll
        for (int k = 1; k < 8; ++k) mx = fmaxf(mx, row[k]);
        float e[8], sum = 0.f;
        #pragma unroll
        for (int k = 0; k < 8; ++k) { e[k] = __expf(row[k] - mx); sum += e[k]; }
        const float inv = 1.f / sum;
        #pragma unroll
        for (int d = 0; d < 32; ++d) {
            float o = 0.f;
            #pragma unroll
            for (int k = 0; k < 8; ++k) o += e[k] * sVv[k * 96 + h0 * 32 + d];
            const int idx = si * 96 + h0 * 32 + d;
            sH[idx] = sQk[idx] + o * inv;
        }
    }
    __syncthreads();

    // fc1: H2 = H + relu(H @ fc1)
    for (int idx = tid; idx < 768; idx += 512) {
        const int s = idx / 96, j = idx % 96;
        const float* W = fc1 + proc * 9216 + j;
        const float* Hs = sH + s * 96;
        float acc = 0.f;
        #pragma unroll 32
        for (int i = 0; i < 96; ++i) acc += Hs[i] * W[i * 96];
        sH2[idx] = sH[idx] + fmaxf(acc, 0.f);
    }
    // Qq = q @ Wq2 (independent — same sync region)
    if (tid < 96) {
        const float* W = Wq2 + proc * 9216 + tid;
        float acc = 0.f;
        #pragma unroll 32
        for (int i = 0; i < 96; ++i) acc += sq[i] * W[i * 96];
        sQq[tid] = acc;
    }
    __syncthreads();

    // K2 = H2 @ Wk2, V2 = H2 @ Wv2
    for (int idx = tid; idx < 1536; idx += 512) {
        const int which = idx / 768, r = idx % 768;
        const int s = r / 96, j = r % 96;
        const float* W = (which ? Wv2 : Wk2) + proc * 9216 + j;
        const float* Hs = sH2 + s * 96;
        float acc = 0.f;
        #pragma unroll 32
        for (int i = 0; i < 96; ++i) acc += Hs[i] * W[i * 96];
        if (which) sV2[r] = acc; else sK2[r] = acc;
    }
    __syncthreads();

    // attn2: 16 heads, d=6, single query row
    if (tid < 16) {
        const int h0 = tid;
        float lg[8], mx = -1e30f;
        #pragma unroll
        for (int k = 0; k < 8; ++k) {
            float acc = 0.f;
            #pragma unroll
            for (int d = 0; d < 6; ++d)
                acc += sQq[h0 * 6 + d] * sK2[k * 96 + h0 * 6 + d];
            lg[k] = acc * rs; mx = fmaxf(mx, lg[k]);
        }
        float e[8], sum = 0.f;
        #pragma unroll
        for (int k = 0; k < 8; ++k) { e[k] = __expf(lg[k] - mx); sum += e[k]; }
        const float inv = 1.f / sum;
        #pragma unroll
        for (int d = 0; d < 6; ++d) {
            float o = 0.f;
            #pragma unroll
            for (int k = 0; k < 8; ++k) o += e[k] * sV2[k * 96 + h0 * 6 + d];
            sO[h0 * 6 + d] = sQq[h0 * 6 + d] + o * inv;
        }
    }
    __syncthreads();

    // fc2: Of = O + relu(O @ fc2)
    if (tid < 96) {
        const float* W = fc2 + proc * 9216 + tid;
        float acc = 0.f;
        #pragma unroll 32
        for (int i = 0; i < 96; ++i) acc += sO[i] * W[i * 96];
        sOf[tid] = sO[tid] + fmaxf(acc, 0.f);
    }
    __syncthreads();

    // Epilogue: trans[m] = Of @ Wo[:,m]; mix with de, alpha, regs, offs
    {
        const int m = tid;
        const float* W = Wo + proc * 49152 + m;
        float tr = 0.f;
        #pragma unroll 32
        for (int h = 0; h < 96; ++h) tr += sOf[h] * W[h * 512];
        const float* Dp = De + proc * 4096 + m * 8;
        float de = 0.f;
        #pragma unroll
        for (int s = 0; s < 8; ++s) de += Dp[s] * sg[s];
        const float a = ws[WS_ALPHA + m];
        const float mix = a * tr + (1.f - a) * de;
        const int pt = proc & 3;                 // gamma gets +1, beta not
        const float off = (pt == 0 || pt == 2) ? 1.f : 0.f;
        out[proc * 512 + m] = mix * regs[proc * 512 + m] + off;
    }
}

extern "C" void kernel_launch(void* const* d_in, const int* in_sizes, int n_in,
                              void* d_out, int out_size, void* d_ws, size_t ws_size,
                              hipStream_t stream)
{
    const float* gate = (const float*)d_in[0];
    const float* x    = (const float*)d_in[1];
    const float* Wa   = (const float*)d_in[2];
    const float* ba   = (const float*)d_in[3];
    const float* Wqr  = (const float*)d_in[4];
    const float* bqr  = (const float*)d_in[5];
    const float* P    = (const float*)d_in[6];
    const float* De   = (const float*)d_in[7];
    const float* regs = (const float*)d_in[8];
    const float* Wq1  = (const float*)d_in[9];
    const float* Wk1  = (const float*)d_in[10];
    const float* Wv1  = (const float*)d_in[11];
    const float* fc1  = (const float*)d_in[12];
    const float* Wq2  = (const float*)d_in[13];
    const float* Wk2  = (const float*)d_in[14];
    const float* Wv2  = (const float*)d_in[15];
    const float* fc2  = (const float*)d_in[16];
    const float* Wo   = (const float*)d_in[17];
    float* ws = (float*)d_ws;

    hipLaunchKernelGGL(k1_qkv_alpha_q, dim3(298), dim3(256), 0, stream,
                       x, Wa, ba, Wqr, bqr, P, Wq1, Wk1, Wv1, ws);
    hipLaunchKernelGGL(k2_attn_out, dim3(8), dim3(512), 0, stream,
                       gate, De, regs, fc1, Wq2, Wk2, Wv2, fc2, Wo, ws,
                       (float*)d_out);
}